// Round 15
// baseline (207.434 us; speedup 1.0000x reference)
//
#include <hip/hip_runtime.h>
#include <math.h>

#define N_NODES 20000
#define E_EDGES 320000
#define HID 256
#define OUT_FEAT 128
#define MPAD 20224           // 316 * 64
#define CAP 64               // bucket capacity per dst (max degree ~45)

#define BK 64
#define LSTR 72              // bf16 LDS row stride (shorts)
#define TSTR 264

typedef __attribute__((ext_vector_type(8))) __bf16 bf16x8;
typedef __attribute__((ext_vector_type(4))) float floatx4;

// ---- int8 row-scaled shadow epilogue: full 64x256 bf16 tile in LDS, 512 thr ----
__device__ __forceinline__ void write_int8_shadow(
    const __bf16 (*tile)[TSTR], int row0, int tid,
    unsigned char* __restrict__ h8, float* __restrict__ scl) {
    const int row = tid >> 3;      // 0..63
    const int seg = tid & 7;       // 32 cols each
    float vals[32];
    float mx = 0.f;
#pragma unroll
    for (int j = 0; j < 32; j++) {
        float v = (float)tile[row][seg * 32 + j];
        vals[j] = v;
        mx = fmaxf(mx, fabsf(v));
    }
#pragma unroll
    for (int m = 1; m <= 4; m <<= 1) mx = fmaxf(mx, __shfl_xor(mx, m));
    const float enc = mx > 0.f ? 127.f / mx : 0.f;
    unsigned int pk[8];
#pragma unroll
    for (int g = 0; g < 8; g++) {
        unsigned int wd = 0;
#pragma unroll
        for (int j = 0; j < 4; j++) {
            int q = (int)rintf(vals[g * 4 + j] * enc);
            q = q > 127 ? 127 : (q < -127 ? -127 : q);
            wd |= ((unsigned int)(q & 0xff)) << (8 * j);
        }
        pk[g] = wd;
    }
    unsigned char* dstp = h8 + (size_t)(row0 + row) * HID + seg * 32;
    *(int4*)dstp        = make_int4(pk[0], pk[1], pk[2], pk[3]);
    *(int4*)(dstp + 16) = make_int4(pk[4], pk[5], pk[6], pk[7]);
    if (seg == 0) scl[row0 + row] = mx * (1.f / 127.f);
}

// ================= front kernel =================
// [0,316): emb GEMM full-width (+int8 shadow); [316,941): scatter; [941,1013): W converts.

#define EMB_BLK 316
#define SCAT_BLK 625
#define CONV_BLK 72

__global__ __launch_bounds__(512) void front_kernel(
    const float* __restrict__ x, const float* __restrict__ wembf,
    __bf16* __restrict__ hb0, unsigned char* __restrict__ h8, float* __restrict__ scl,
    const int* __restrict__ src, const int* __restrict__ dst,
    const float* __restrict__ w, int* __restrict__ counts, int2* __restrict__ edges,
    const float* __restrict__ w1f, const float* __restrict__ w2f, const float* __restrict__ wfcf,
    __bf16* __restrict__ w1b, __bf16* __restrict__ w2b, __bf16* __restrict__ wfcb)
{
    __shared__ __bf16 smem[64 * LSTR + 256 * LSTR];
    const int bid = blockIdx.x;
    const int tid = threadIdx.x;

    if (bid < EMB_BLK) {
        __bf16* As = smem;
        __bf16* Bs = smem + 64 * LSTR;
        const int row0 = bid * 64;
        const int wv = tid >> 6, l = tid & 63, lr = l & 15, lq = l >> 4;
        const int wm = wv & 1, wn4 = wv >> 1;

        floatx4 acc[2][4];
#pragma unroll
        for (int i = 0; i < 2; i++)
#pragma unroll
            for (int j = 0; j < 4; j++) acc[i][j] = (floatx4){0.f, 0.f, 0.f, 0.f};

        const int srow = tid >> 3;
        const int skq = (tid & 7) * 8;

        for (int kc = 0; kc < 256; kc += BK) {
            {
                int grow = row0 + srow;
                float4 v0 = make_float4(0.f, 0.f, 0.f, 0.f), v1 = v0;
                if (grow < N_NODES) {
                    const float* xp = x + (size_t)grow * HID + kc + skq;
                    v0 = *(const float4*)xp;
                    v1 = *(const float4*)(xp + 4);
                }
                bf16x8 o;
                o[0] = (__bf16)v0.x; o[1] = (__bf16)v0.y; o[2] = (__bf16)v0.z; o[3] = (__bf16)v0.w;
                o[4] = (__bf16)v1.x; o[5] = (__bf16)v1.y; o[6] = (__bf16)v1.z; o[7] = (__bf16)v1.w;
                *(bf16x8*)&As[srow * LSTR + skq] = o;
            }
#pragma unroll
            for (int r = 0; r < 4; r++) {
                int row = r * 64 + srow;
                const float* wp = wembf + (size_t)row * 256 + kc + skq;
                float4 v0 = *(const float4*)wp;
                float4 v1 = *(const float4*)(wp + 4);
                bf16x8 o;
                o[0] = (__bf16)v0.x; o[1] = (__bf16)v0.y; o[2] = (__bf16)v0.z; o[3] = (__bf16)v0.w;
                o[4] = (__bf16)v1.x; o[5] = (__bf16)v1.y; o[6] = (__bf16)v1.z; o[7] = (__bf16)v1.w;
                *(bf16x8*)&Bs[row * LSTR + skq] = o;
            }
            __syncthreads();
#pragma unroll
            for (int s = 0; s < 2; s++) {
                bf16x8 af[2], bfr[4];
#pragma unroll
                for (int mt = 0; mt < 2; mt++)
                    af[mt] = *(const bf16x8*)&As[(wm * 32 + mt * 16 + lr) * LSTR + s * 32 + lq * 8];
#pragma unroll
                for (int nt = 0; nt < 4; nt++)
                    bfr[nt] = *(const bf16x8*)&Bs[(wn4 * 64 + nt * 16 + lr) * LSTR + s * 32 + lq * 8];
#pragma unroll
                for (int mt = 0; mt < 2; mt++)
#pragma unroll
                    for (int nt = 0; nt < 4; nt++)
                        acc[mt][nt] = __builtin_amdgcn_mfma_f32_16x16x32_bf16(af[mt], bfr[nt], acc[mt][nt], 0, 0, 0);
            }
            __syncthreads();
        }
        __bf16 (*tile)[TSTR] = (__bf16(*)[TSTR])smem;
#pragma unroll
        for (int nt = 0; nt < 4; nt++) {
            const int col = wn4 * 64 + nt * 16 + lr;
#pragma unroll
            for (int mt = 0; mt < 2; mt++) {
                const int lrow = wm * 32 + mt * 16 + lq * 4;
#pragma unroll
                for (int r = 0; r < 4; r++) {
                    float v = acc[mt][nt][r];
                    hb0[(size_t)(row0 + lrow + r) * HID + col] = (__bf16)v;
                    tile[lrow + r][col] = (__bf16)v;
                }
            }
        }
        __syncthreads();
        write_int8_shadow(tile, row0, tid, h8, scl);
    } else if (bid < EMB_BLK + SCAT_BLK) {
        int e = (bid - EMB_BLK) * 512 + tid;
        int d = dst[e];
        int p = atomicAdd(&counts[d], 1);
        edges[(size_t)d * CAP + p] = make_int2(src[e], __float_as_int(w[e]));
    } else {
        // convert W1/W2/Wfc f32->bf16 (294912 floats = 72*512*8)
        const size_t gi = ((size_t)(bid - EMB_BLK - SCAT_BLK) * 512 + tid) * 8;
        const size_t s1 = 131072, s2 = 262144;
        const float* sp; __bf16* dp; size_t off;
        if (gi < s1)      { sp = w1f; dp = w1b; off = gi; }
        else if (gi < s2) { sp = w2f; dp = w2b; off = gi - s1; }
        else              { sp = wfcf; dp = wfcb; off = gi - s2; }
        float4 v0 = *(const float4*)(sp + off);
        float4 v1 = *(const float4*)(sp + off + 4);
        bf16x8 o;
        o[0] = (__bf16)v0.x; o[1] = (__bf16)v0.y; o[2] = (__bf16)v0.z; o[3] = (__bf16)v0.w;
        o[4] = (__bf16)v1.x; o[5] = (__bf16)v1.y; o[6] = (__bf16)v1.z; o[7] = (__bf16)v1.w;
        *(bf16x8*)(dp + off) = o;
    }
}

// ================= merged: aggregation ∥ gconv phase-1 =================
// blocks [0,1250): agg (int8 gather, 16 dsts/block, bf16 out)
// blocks [1250,1566): gconv phase-1: pacc = hp @ Wl^T (K 0..255), f32 out

#define AGG_BLK 1250

__global__ __launch_bounds__(512) void agg_gemmL_kernel(
    const unsigned char* __restrict__ h8, const float* __restrict__ scl,
    const int* __restrict__ counts, const int2* __restrict__ edges,
    __bf16* __restrict__ aggb,
    const __bf16* __restrict__ hp,   // [MPAD,256]
    const __bf16* __restrict__ W,    // [256,512] (left half used)
    float* __restrict__ pacc)        // [MPAD,256] f32
{
    __shared__ __bf16 smem[64 * LSTR + 256 * LSTR];
    const int tid = threadIdx.x;

    if (blockIdx.x < AGG_BLK) {
        // ---- agg role ----
        const int wave = tid >> 6, lane = tid & 63;
        const int half = lane >> 5, lh = lane & 31;
        const int d = blockIdx.x * 16 + wave * 2 + half;
        const size_t base = (size_t)d * CAP;
        const int cnt = counts[d];
        const int iters = (cnt + 7) >> 3;
        float acc[8];
#pragma unroll
        for (int q = 0; q < 8; q++) acc[q] = 0.f;

        for (int it = 0; it < iters; ++it) {
            const int jb = it * 8;
            const int2* ep = edges + base + jb;
            int4 eh[4];
#pragma unroll
            for (int u = 0; u < 4; u++) eh[u] = *(const int4*)(ep + u * 2);
            int sidx[8]; float ew[8];
#pragma unroll
            for (int u = 0; u < 4; u++) {
                const bool m0 = (jb + u * 2)     < cnt;
                const bool m1 = (jb + u * 2 + 1) < cnt;
                sidx[u * 2]     = m0 ? eh[u].x : 0;
                ew[u * 2]       = m0 ? __int_as_float(eh[u].y) : 0.f;
                sidx[u * 2 + 1] = m1 ? eh[u].z : 0;
                ew[u * 2 + 1]   = m1 ? __int_as_float(eh[u].w) : 0.f;
            }
            float ws8[8];
#pragma unroll
            for (int u = 0; u < 8; u++) ws8[u] = ew[u] * scl[sidx[u]];
            uint2 hv[8];
#pragma unroll
            for (int u = 0; u < 8; u++)
                hv[u] = *(const uint2*)(h8 + (size_t)sidx[u] * HID + lh * 8);
#pragma unroll
            for (int u = 0; u < 8; u++) {
                const unsigned int a = hv[u].x, b = hv[u].y;
                const float wu = ws8[u];
                acc[0] = fmaf(wu, (float)(int)(signed char)(a),       acc[0]);
                acc[1] = fmaf(wu, (float)(int)(signed char)(a >> 8),  acc[1]);
                acc[2] = fmaf(wu, (float)(int)(signed char)(a >> 16), acc[2]);
                acc[3] = fmaf(wu, (float)(int)(signed char)(a >> 24), acc[3]);
                acc[4] = fmaf(wu, (float)(int)(signed char)(b),       acc[4]);
                acc[5] = fmaf(wu, (float)(int)(signed char)(b >> 8),  acc[5]);
                acc[6] = fmaf(wu, (float)(int)(signed char)(b >> 16), acc[6]);
                acc[7] = fmaf(wu, (float)(int)(signed char)(b >> 24), acc[7]);
            }
        }
        bf16x8 o;
#pragma unroll
        for (int q = 0; q < 8; q++) o[q] = (__bf16)acc[q];
        *(bf16x8*)(aggb + (size_t)d * HID + lh * 8) = o;
    } else {
        // ---- gconv phase-1 role: pacc = hp @ Wl^T ----
        __bf16* As = smem;
        __bf16* Bs = smem + 64 * LSTR;
        const int row0 = (blockIdx.x - AGG_BLK) * 64;
        const int wv = tid >> 6, l = tid & 63, lr = l & 15, lq = l >> 4;
        const int wm = wv & 1, wn4 = wv >> 1;

        floatx4 acc[2][4];
#pragma unroll
        for (int i = 0; i < 2; i++)
#pragma unroll
            for (int j = 0; j < 4; j++) acc[i][j] = (floatx4){0.f, 0.f, 0.f, 0.f};

        const int srow = tid >> 3;
        const int skq = (tid & 7) * 8;

        for (int kc = 0; kc < 256; kc += BK) {
            *(bf16x8*)&As[srow * LSTR + skq] =
                *(const bf16x8*)(hp + (size_t)(row0 + srow) * HID + kc + skq);
#pragma unroll
            for (int r = 0; r < 4; r++) {
                int row = r * 64 + srow;
                *(bf16x8*)&Bs[row * LSTR + skq] =
                    *(const bf16x8*)(W + (size_t)row * 512 + kc + skq);
            }
            __syncthreads();
#pragma unroll
            for (int s = 0; s < 2; s++) {
                bf16x8 af[2], bfr[4];
#pragma unroll
                for (int mt = 0; mt < 2; mt++)
                    af[mt] = *(const bf16x8*)&As[(wm * 32 + mt * 16 + lr) * LSTR + s * 32 + lq * 8];
#pragma unroll
                for (int nt = 0; nt < 4; nt++)
                    bfr[nt] = *(const bf16x8*)&Bs[(wn4 * 64 + nt * 16 + lr) * LSTR + s * 32 + lq * 8];
#pragma unroll
                for (int mt = 0; mt < 2; mt++)
#pragma unroll
                    for (int nt = 0; nt < 4; nt++)
                        acc[mt][nt] = __builtin_amdgcn_mfma_f32_16x16x32_bf16(af[mt], bfr[nt], acc[mt][nt], 0, 0, 0);
            }
            __syncthreads();
        }
#pragma unroll
        for (int nt = 0; nt < 4; nt++) {
            const int col = wn4 * 64 + nt * 16 + lr;
#pragma unroll
            for (int mt = 0; mt < 2; mt++) {
                const int lrow = wm * 32 + mt * 16 + lq * 4;
#pragma unroll
                for (int r = 0; r < 4; r++)
                    pacc[(size_t)(row0 + lrow + r) * HID + col] = acc[mt][nt][r];
            }
        }
    }
}

// ================= gconv phase-2 + epilogue (optional fc+norm) =================
// 4 bf16 chunks: acc = ag @ Wr^T; epilogue: v = hp + relu(pacc + acc + b).

template <bool LAST>
__global__ __launch_bounds__(512) void gconvR_kernel(
    const __bf16* __restrict__ hp,     // [MPAD,256] residual
    const __bf16* __restrict__ ag,     // [MPAD,256] agg (bf16)
    const __bf16* __restrict__ W,      // [256,512] (right half used)
    const float* __restrict__ pacc,    // [MPAD,256] f32 phase-1 partial
    const float* __restrict__ bias,
    __bf16* __restrict__ hn, unsigned char* __restrict__ h8, float* __restrict__ scl, // !LAST
    const __bf16* __restrict__ Wfc, float* __restrict__ outp)                         // LAST
{
    __shared__ __bf16 smem[64 * LSTR + 256 * LSTR];
    __bf16* As = smem;
    __bf16* Bs = smem + 64 * LSTR;
    const int tid = threadIdx.x;
    const int row0 = blockIdx.x * 64;
    const int wv = tid >> 6, l = tid & 63, lr = l & 15, lq = l >> 4;
    const int wm = wv & 1, wn4 = wv >> 1;

    floatx4 acc[2][4];
#pragma unroll
    for (int i = 0; i < 2; i++)
#pragma unroll
        for (int j = 0; j < 4; j++) acc[i][j] = (floatx4){0.f, 0.f, 0.f, 0.f};

    const int srow = tid >> 3;
    const int skq = (tid & 7) * 8;

    for (int kc = 0; kc < 256; kc += BK) {
        *(bf16x8*)&As[srow * LSTR + skq] =
            *(const bf16x8*)(ag + (size_t)(row0 + srow) * HID + kc + skq);
#pragma unroll
        for (int r = 0; r < 4; r++) {
            int row = r * 64 + srow;
            *(bf16x8*)&Bs[row * LSTR + skq] =
                *(const bf16x8*)(W + (size_t)row * 512 + 256 + kc + skq);
        }
        __syncthreads();
#pragma unroll
        for (int s = 0; s < 2; s++) {
            bf16x8 af[2], bfr[4];
#pragma unroll
            for (int mt = 0; mt < 2; mt++)
                af[mt] = *(const bf16x8*)&As[(wm * 32 + mt * 16 + lr) * LSTR + s * 32 + lq * 8];
#pragma unroll
            for (int nt = 0; nt < 4; nt++)
                bfr[nt] = *(const bf16x8*)&Bs[(wn4 * 64 + nt * 16 + lr) * LSTR + s * 32 + lq * 8];
#pragma unroll
            for (int mt = 0; mt < 2; mt++)
#pragma unroll
                for (int nt = 0; nt < 4; nt++)
                    acc[mt][nt] = __builtin_amdgcn_mfma_f32_16x16x32_bf16(af[mt], bfr[nt], acc[mt][nt], 0, 0, 0);
        }
        __syncthreads();
    }

    // epilogue: v = hp + relu(pacc + acc + b) -> tile (+ hn when !LAST)
    __bf16 (*tile)[TSTR] = (__bf16(*)[TSTR])smem;
#pragma unroll
    for (int nt = 0; nt < 4; nt++) {
        const int col = wn4 * 64 + nt * 16 + lr;
        const float b = bias[col];
#pragma unroll
        for (int mt = 0; mt < 2; mt++) {
            const int lrow = wm * 32 + mt * 16 + lq * 4;
#pragma unroll
            for (int r = 0; r < 4; r++) {
                const int row = row0 + lrow + r;
                float gem = acc[mt][nt][r] + pacc[(size_t)row * HID + col];
                float res = (float)hp[(size_t)row * HID + col];
                float v = res + fmaxf(gem + b, 0.f);
                if (!LAST) hn[(size_t)row * HID + col] = (__bf16)v;
                tile[lrow + r][col] = (__bf16)v;
            }
        }
    }
    __syncthreads();

    if (!LAST) {
        write_int8_shadow(tile, row0, tid, h8, scl);
    } else if (wv < 4) {
        // fc: 16 rows/wave x 128 cols, K=256, A from LDS h2 tile; then L2-normalize
        floatx4 facc[8];
#pragma unroll
        for (int j = 0; j < 8; j++) facc[j] = (floatx4){0.f, 0.f, 0.f, 0.f};
#pragma unroll
        for (int kt = 0; kt < 256; kt += 32) {
            bf16x8 a = *(const bf16x8*)&tile[wv * 16 + lr][kt + lq * 8];
            bf16x8 bf8[8];
#pragma unroll
            for (int nt = 0; nt < 8; nt++)
                bf8[nt] = *(const bf16x8*)(Wfc + (size_t)(nt * 16 + lr) * 256 + kt + lq * 8);
#pragma unroll
            for (int nt = 0; nt < 8; nt++)
                facc[nt] = __builtin_amdgcn_mfma_f32_16x16x32_bf16(a, bf8[nt], facc[nt], 0, 0, 0);
        }
        float s[4];
#pragma unroll
        for (int r = 0; r < 4; r++) {
            float t = 0.f;
#pragma unroll
            for (int nt = 0; nt < 8; nt++) t = fmaf(facc[nt][r], facc[nt][r], t);
            s[r] = t;
        }
#pragma unroll
        for (int mask = 1; mask <= 8; mask <<= 1) {
#pragma unroll
            for (int r = 0; r < 4; r++) s[r] += __shfl_xor(s[r], mask);
        }
        float inv[4];
#pragma unroll
        for (int r = 0; r < 4; r++) inv[r] = rsqrtf(s[r]);
#pragma unroll
        for (int r = 0; r < 4; r++) {
            int row = row0 + wv * 16 + lq * 4 + r;
            if (row >= N_NODES) continue;
#pragma unroll
            for (int nt = 0; nt < 8; nt++)
                outp[(size_t)row * OUT_FEAT + nt * 16 + lr] = facc[nt][r] * inv[r];
        }
    }
}

// ================= launch =================

extern "C" void kernel_launch(void* const* d_in, const int* in_sizes, int n_in,
                              void* d_out, int out_size, void* d_ws, size_t ws_size,
                              hipStream_t stream) {
    const float* x        = (const float*)d_in[0];
    const int*   edge_src = (const int*)d_in[1];
    const int*   edge_dst = (const int*)d_in[2];
    const float* edge_w   = (const float*)d_in[3];
    const float* W_emb    = (const float*)d_in[4];
    const float* W_gc1    = (const float*)d_in[5];
    const float* b_gc1    = (const float*)d_in[6];
    const float* W_gc2    = (const float*)d_in[7];
    const float* b_gc2    = (const float*)d_in[8];
    const float* W_fc     = (const float*)d_in[9];
    float* out = (float*)d_out;

    // ---- workspace layout ----
    char* p = (char*)d_ws;
    const size_t HROW = (size_t)MPAD * HID;
    __bf16* hb0   = (__bf16*)p;             p += HROW * 2;        // h0
    __bf16* hb1   = (__bf16*)p;             p += HROW * 2;        // h1
    __bf16* aggb  = (__bf16*)p;             p += HROW * 2;        // agg (bf16)
    unsigned char* h8 = (unsigned char*)p;  p += HROW;            // int8 h shadow
    float*  scl   = (float*)p;              p += (size_t)MPAD * 4;
    float*  pacc  = (float*)p;              p += HROW * 4;        // f32 phase-1 partial
    __bf16* w1b   = (__bf16*)p;             p += 131072 * 2;
    __bf16* w2b   = (__bf16*)p;             p += 131072 * 2;
    __bf16* wfcb  = (__bf16*)p;             p += 32768 * 2;
    int2*   edges = (int2*)p;               p += (size_t)N_NODES * CAP * 8;
    int*    counts = (int*)p;               p += (size_t)MPAD * 4;

    // N1: zero counts
    hipMemsetAsync(counts, 0, (size_t)MPAD * 4, stream);

    // N2: emb GEMM (+int8 shadow) + scatter + W convert
    front_kernel<<<EMB_BLK + SCAT_BLK + CONV_BLK, 512, 0, stream>>>(
        x, W_emb, hb0, h8, scl, edge_src, edge_dst, edge_w, counts, edges,
        W_gc1, W_gc2, W_fc, w1b, w2b, wfcb);

    // N3: agg1 (int8 gather) ∥ gconv1 phase-1 (pacc = h0 @ W1l^T)
    agg_gemmL_kernel<<<AGG_BLK + 316, 512, 0, stream>>>(
        h8, scl, counts, edges, aggb, hb0, w1b, pacc);

    // N4: h1 = h0 + relu(pacc + agg1 @ W1r^T + b1) (+int8 shadow)
    gconvR_kernel<false><<<316, 512, 0, stream>>>(
        hb0, aggb, w1b, pacc, b_gc1, hb1, h8, scl, nullptr, nullptr);

    // N5: agg2 ∥ gconv2 phase-1 (pacc = h1 @ W2l^T)
    agg_gemmL_kernel<<<AGG_BLK + 316, 512, 0, stream>>>(
        h8, scl, counts, edges, aggb, hb1, w2b, pacc);

    // N6: h2 = h1 + relu(pacc + agg2 @ W2r^T + b2); out = normalize(h2 @ Wfc^T)
    gconvR_kernel<true><<<316, 512, 0, stream>>>(
        hb1, aggb, w2b, pacc, b_gc2, nullptr, nullptr, nullptr, wfcb, out);
}

// Round 16
// 203.044 us; speedup vs baseline: 1.0216x; 1.0216x over previous
//
#include <hip/hip_runtime.h>
#include <math.h>

#define N_NODES 20000
#define E_EDGES 320000
#define HID 256
#define OUT_FEAT 128
#define MPAD 20224           // 316 * 64
#define CAP 64               // bucket capacity per dst (max degree ~45)

#define BK 64
#define LSTR 72              // LDS row stride in shorts (64 + 8 pad)
#define TSTR 264

typedef __attribute__((ext_vector_type(8))) __bf16 bf16x8;
typedef __attribute__((ext_vector_type(4))) float floatx4;

// ---- int8 row-scaled shadow epilogue (shared by emb / gconv1) ----
// tile[64][TSTR] holds the block's 64x256 bf16 rows; 512 threads: 8 per row.
__device__ __forceinline__ void write_int8_shadow(
    const __bf16 (*tile)[TSTR], int row0, int tid,
    unsigned char* __restrict__ h8, float* __restrict__ scl) {
    const int row = tid >> 3;      // 0..63
    const int seg = tid & 7;       // 32 cols each
    float vals[32];
    float mx = 0.f;
#pragma unroll
    for (int j = 0; j < 32; j++) {
        float v = (float)tile[row][seg * 32 + j];
        vals[j] = v;
        mx = fmaxf(mx, fabsf(v));
    }
#pragma unroll
    for (int m = 1; m <= 4; m <<= 1) mx = fmaxf(mx, __shfl_xor(mx, m));
    const float enc = mx > 0.f ? 127.f / mx : 0.f;
    unsigned int pk[8];
#pragma unroll
    for (int g = 0; g < 8; g++) {
        unsigned int wd = 0;
#pragma unroll
        for (int j = 0; j < 4; j++) {
            int q = (int)rintf(vals[g * 4 + j] * enc);
            q = q > 127 ? 127 : (q < -127 ? -127 : q);
            wd |= ((unsigned int)(q & 0xff)) << (8 * j);
        }
        pk[g] = wd;
    }
    unsigned char* dstp = h8 + (size_t)(row0 + row) * HID + seg * 32;
    *(int4*)dstp        = make_int4(pk[0], pk[1], pk[2], pk[3]);
    *(int4*)(dstp + 16) = make_int4(pk[4], pk[5], pk[6], pk[7]);
    if (seg == 0) scl[row0 + row] = mx * (1.f / 127.f);
}

// ================= front kernel: emb GEMM (full-width) + scatter + W convert =================
// blocks [0,316): emb BM=64 x BN=256, 512 thr; [316,941): scatter; [941,1013): convert.

#define EMB_BLK 316
#define SCAT_BLK 625
#define CONV_BLK 72

__global__ __launch_bounds__(512) void front_kernel(
    const float* __restrict__ x,       // [20000,256] f32
    const float* __restrict__ wembf,   // [256,256] f32
    __bf16* __restrict__ hb0,          // [MPAD,256]
    unsigned char* __restrict__ h8,    // [MPAD,256] int8 shadow
    float* __restrict__ scl,           // [MPAD] row scales
    const int* __restrict__ src, const int* __restrict__ dst,
    const float* __restrict__ w, int* __restrict__ counts,
    int2* __restrict__ edges,
    const float* __restrict__ w1f, const float* __restrict__ w2f,
    const float* __restrict__ wfcf,
    __bf16* __restrict__ w1b, __bf16* __restrict__ w2b,
    __bf16* __restrict__ wfcb)
{
    __shared__ __bf16 smem[64 * LSTR + 256 * LSTR];   // 46 KB
    const int bid = blockIdx.x;
    const int tid = threadIdx.x;

    if (bid < EMB_BLK) {
        __bf16* As = smem;
        __bf16* Bs = smem + 64 * LSTR;
        const int row0 = bid * 64;
        const int wv = tid >> 6, l = tid & 63, lr = l & 15, lq = l >> 4;
        const int wm = wv & 1, wn4 = wv >> 1;

        floatx4 acc[2][4];
#pragma unroll
        for (int i = 0; i < 2; i++)
#pragma unroll
            for (int j = 0; j < 4; j++) acc[i][j] = (floatx4){0.f, 0.f, 0.f, 0.f};

        const int srow = tid >> 3;          // 0..63
        const int skq = (tid & 7) * 8;

        for (int kc = 0; kc < 256; kc += BK) {
            // stage A (x f32, row-guarded): 64 rows, 1 round
            {
                int grow = row0 + srow;
                float4 v0 = make_float4(0.f, 0.f, 0.f, 0.f), v1 = v0;
                if (grow < N_NODES) {
                    const float* xp = x + (size_t)grow * HID + kc + skq;
                    v0 = *(const float4*)xp;
                    v1 = *(const float4*)(xp + 4);
                }
                bf16x8 o;
                o[0] = (__bf16)v0.x; o[1] = (__bf16)v0.y; o[2] = (__bf16)v0.z; o[3] = (__bf16)v0.w;
                o[4] = (__bf16)v1.x; o[5] = (__bf16)v1.y; o[6] = (__bf16)v1.z; o[7] = (__bf16)v1.w;
                *(bf16x8*)&As[srow * LSTR + skq] = o;
            }
            // stage B (W_emb f32): 256 rows, 4 rounds
#pragma unroll
            for (int r = 0; r < 4; r++) {
                int row = r * 64 + srow;
                const float* wp = wembf + (size_t)row * 256 + kc + skq;
                float4 v0 = *(const float4*)wp;
                float4 v1 = *(const float4*)(wp + 4);
                bf16x8 o;
                o[0] = (__bf16)v0.x; o[1] = (__bf16)v0.y; o[2] = (__bf16)v0.z; o[3] = (__bf16)v0.w;
                o[4] = (__bf16)v1.x; o[5] = (__bf16)v1.y; o[6] = (__bf16)v1.z; o[7] = (__bf16)v1.w;
                *(bf16x8*)&Bs[row * LSTR + skq] = o;
            }
            __syncthreads();
#pragma unroll
            for (int s = 0; s < 2; s++) {
                bf16x8 af[2], bfr[4];
#pragma unroll
                for (int mt = 0; mt < 2; mt++)
                    af[mt] = *(const bf16x8*)&As[(wm * 32 + mt * 16 + lr) * LSTR + s * 32 + lq * 8];
#pragma unroll
                for (int nt = 0; nt < 4; nt++)
                    bfr[nt] = *(const bf16x8*)&Bs[(wn4 * 64 + nt * 16 + lr) * LSTR + s * 32 + lq * 8];
#pragma unroll
                for (int mt = 0; mt < 2; mt++)
#pragma unroll
                    for (int nt = 0; nt < 4; nt++)
                        acc[mt][nt] = __builtin_amdgcn_mfma_f32_16x16x32_bf16(af[mt], bfr[nt], acc[mt][nt], 0, 0, 0);
            }
            __syncthreads();
        }
        // epilogue: write global bf16 + LDS tile, then int8 shadow
        __bf16 (*tile)[TSTR] = (__bf16(*)[TSTR])smem;
#pragma unroll
        for (int nt = 0; nt < 4; nt++) {
            const int col = wn4 * 64 + nt * 16 + lr;
#pragma unroll
            for (int mt = 0; mt < 2; mt++) {
                const int lrow = wm * 32 + mt * 16 + lq * 4;
#pragma unroll
                for (int r = 0; r < 4; r++) {
                    float v = acc[mt][nt][r];
                    hb0[(size_t)(row0 + lrow + r) * HID + col] = (__bf16)v;
                    tile[lrow + r][col] = (__bf16)v;
                }
            }
        }
        __syncthreads();
        write_int8_shadow(tile, row0, tid, h8, scl);
    } else if (bid < EMB_BLK + SCAT_BLK) {
        // ---- scatter (625*512 == 320000 exactly) ----
        int e = (bid - EMB_BLK) * 512 + tid;
        int d = dst[e];
        int p = atomicAdd(&counts[d], 1);
        edges[(size_t)d * CAP + p] = make_int2(src[e], __float_as_int(w[e]));
    } else {
        // ---- convert W1/W2/Wfc (294912 floats, 72*512*8 exactly) ----
        const size_t gi = ((size_t)(bid - EMB_BLK - SCAT_BLK) * 512 + tid) * 8;
        const size_t s1 = 131072, s2 = 262144;
        const float* srcp; __bf16* dstp; size_t off;
        if (gi < s1)      { srcp = w1f; dstp = w1b; off = gi; }
        else if (gi < s2) { srcp = w2f; dstp = w2b; off = gi - s1; }
        else              { srcp = wfcf; dstp = wfcb; off = gi - s2; }
        float4 v0 = *(const float4*)(srcp + off);
        float4 v1 = *(const float4*)(srcp + off + 4);
        bf16x8 o;
        o[0] = (__bf16)v0.x; o[1] = (__bf16)v0.y; o[2] = (__bf16)v0.z; o[3] = (__bf16)v0.w;
        o[4] = (__bf16)v1.x; o[5] = (__bf16)v1.y; o[6] = (__bf16)v1.z; o[7] = (__bf16)v1.w;
        *(bf16x8*)(dstp + off) = o;
    }
}

// ================= aggregation: agg[d] = sum_e w_e * h[src_e] =================
// half-wave per dst; uniform 16-edge loop, arithmetic tail masking.
// Gathers int8 rows (256 B/row, 8 B/lane); combined weight = w_e * scl[src].

__global__ __launch_bounds__(256) void aggregate_kernel(
    const unsigned char* __restrict__ h8, const float* __restrict__ scl,
    const int* __restrict__ counts,
    const int2* __restrict__ edges, __bf16* __restrict__ agg) {
    const int w = threadIdx.x >> 6, lane = threadIdx.x & 63;
    const int half = lane >> 5, lh = lane & 31;
    const int d = blockIdx.x * 8 + w * 2 + half;
    const size_t base = (size_t)d * CAP;
    const int cnt = counts[d];
    const int iters = (cnt + 15) >> 4;
    float acc[8];
#pragma unroll
    for (int q = 0; q < 8; q++) acc[q] = 0.f;

    for (int it = 0; it < iters; ++it) {
        const int jb = it * 16;
        const int2* ep = edges + base + jb;
        int4 eh[8];
#pragma unroll
        for (int u = 0; u < 8; u++) eh[u] = *(const int4*)(ep + u * 2);
        int sidx[16]; float ew[16];
#pragma unroll
        for (int u = 0; u < 8; u++) {
            const bool m0 = (jb + u * 2)     < cnt;
            const bool m1 = (jb + u * 2 + 1) < cnt;
            sidx[u * 2]     = m0 ? eh[u].x : 0;
            ew[u * 2]       = m0 ? __int_as_float(eh[u].y) : 0.f;
            sidx[u * 2 + 1] = m1 ? eh[u].z : 0;
            ew[u * 2 + 1]   = m1 ? __int_as_float(eh[u].w) : 0.f;
        }
        float ws[16];
#pragma unroll
        for (int u = 0; u < 16; u++) ws[u] = ew[u] * scl[sidx[u]];
        uint2 hv[16];
#pragma unroll
        for (int u = 0; u < 16; u++)
            hv[u] = *(const uint2*)(h8 + (size_t)sidx[u] * HID + lh * 8);
#pragma unroll
        for (int u = 0; u < 16; u++) {
            const unsigned int a = hv[u].x, b = hv[u].y;
            const float wu = ws[u];
            acc[0] = fmaf(wu, (float)(int)(signed char)(a),       acc[0]);
            acc[1] = fmaf(wu, (float)(int)(signed char)(a >> 8),  acc[1]);
            acc[2] = fmaf(wu, (float)(int)(signed char)(a >> 16), acc[2]);
            acc[3] = fmaf(wu, (float)(int)(signed char)(a >> 24), acc[3]);
            acc[4] = fmaf(wu, (float)(int)(signed char)(b),       acc[4]);
            acc[5] = fmaf(wu, (float)(int)(signed char)(b >> 8),  acc[5]);
            acc[6] = fmaf(wu, (float)(int)(signed char)(b >> 16), acc[6]);
            acc[7] = fmaf(wu, (float)(int)(signed char)(b >> 24), acc[7]);
        }
    }
    bf16x8 o;
#pragma unroll
    for (int q = 0; q < 8; q++) o[q] = (__bf16)acc[q];
    *(bf16x8*)(agg + (size_t)d * HID + lh * 8) = o;
}

// ================= gconv1 (full-width): hn = hp + relu([hp|ag] @ W^T + b) =================
// BM=64, BN=256, 512 thr = 8 waves; also writes int8 shadow of hn.

__global__ __launch_bounds__(512) void gconv1_kernel(
    const __bf16* __restrict__ hp,     // [MPAD,256]
    const __bf16* __restrict__ ag,     // [MPAD,256]
    const __bf16* __restrict__ W,      // [256,512]
    const float* __restrict__ bias,    // [256]
    __bf16* __restrict__ hn,           // [MPAD,256]
    unsigned char* __restrict__ h8,    // [MPAD,256] int8 shadow of hn
    float* __restrict__ scl)           // [MPAD]
{
    __shared__ __bf16 smem[64 * LSTR + 256 * LSTR];
    __bf16* As = smem;
    __bf16* Bs = smem + 64 * LSTR;
    const int tid = threadIdx.x;
    const int row0 = blockIdx.x * 64;
    const int wv = tid >> 6, l = tid & 63, lr = l & 15, lq = l >> 4;
    const int wm = wv & 1, wn4 = wv >> 1;

    floatx4 acc[2][4];
#pragma unroll
    for (int i = 0; i < 2; i++)
#pragma unroll
        for (int j = 0; j < 4; j++) acc[i][j] = (floatx4){0.f, 0.f, 0.f, 0.f};

    const int srow = tid >> 3;          // 0..63
    const int skq = (tid & 7) * 8;

    for (int kc = 0; kc < 512; kc += BK) {
        const __bf16* Asrc = (kc >= 256) ? ag : hp;
        const int ks = kc & 255;
        *(bf16x8*)&As[srow * LSTR + skq] =
            *(const bf16x8*)(Asrc + (size_t)(row0 + srow) * HID + ks + skq);
#pragma unroll
        for (int r = 0; r < 4; r++) {
            int row = r * 64 + srow;
            *(bf16x8*)&Bs[row * LSTR + skq] =
                *(const bf16x8*)(W + (size_t)row * 512 + kc + skq);
        }
        __syncthreads();
#pragma unroll
        for (int s = 0; s < 2; s++) {
            bf16x8 af[2], bfr[4];
#pragma unroll
            for (int mt = 0; mt < 2; mt++)
                af[mt] = *(const bf16x8*)&As[(wm * 32 + mt * 16 + lr) * LSTR + s * 32 + lq * 8];
#pragma unroll
            for (int nt = 0; nt < 4; nt++)
                bfr[nt] = *(const bf16x8*)&Bs[(wn4 * 64 + nt * 16 + lr) * LSTR + s * 32 + lq * 8];
#pragma unroll
            for (int mt = 0; mt < 2; mt++)
#pragma unroll
                for (int nt = 0; nt < 4; nt++)
                    acc[mt][nt] = __builtin_amdgcn_mfma_f32_16x16x32_bf16(af[mt], bfr[nt], acc[mt][nt], 0, 0, 0);
        }
        __syncthreads();
    }

    // epilogue: hn = hp + relu(acc+b) -> global + LDS tile -> int8 shadow
    __bf16 (*tile)[TSTR] = (__bf16(*)[TSTR])smem;
#pragma unroll
    for (int nt = 0; nt < 4; nt++) {
        const int col = wn4 * 64 + nt * 16 + lr;
        const float b = bias[col];
#pragma unroll
        for (int mt = 0; mt < 2; mt++) {
            const int lrow = wm * 32 + mt * 16 + lq * 4;
#pragma unroll
            for (int r = 0; r < 4; r++) {
                float res = (float)hp[(size_t)(row0 + lrow + r) * HID + col];
                float v = res + fmaxf(acc[mt][nt][r] + b, 0.f);
                hn[(size_t)(row0 + lrow + r) * HID + col] = (__bf16)v;
                tile[lrow + r][col] = (__bf16)v;
            }
        }
    }
    __syncthreads();
    write_int8_shadow(tile, row0, tid, h8, scl);
}

// ================= gconv2 + fc + normalize fused =================

__global__ __launch_bounds__(512) void gconv_fc_kernel(
    const __bf16* __restrict__ hp,     // [MPAD,256] h1
    const __bf16* __restrict__ ag,     // [MPAD,256] agg2
    const __bf16* __restrict__ W,      // [256,512]
    const float* __restrict__ bias,    // [256]
    const __bf16* __restrict__ Wfc,    // [128,256]
    float* __restrict__ outp)          // [20000,128]
{
    __shared__ __bf16 smem[64 * LSTR + 256 * LSTR];
    __bf16* As = smem;
    __bf16* Bs = smem + 64 * LSTR;
    const int tid = threadIdx.x;
    const int row0 = blockIdx.x * 64;
    const int wv = tid >> 6, l = tid & 63, lr = l & 15, lq = l >> 4;
    const int wm = wv & 1, wn4 = wv >> 1;

    floatx4 acc[2][4];
#pragma unroll
    for (int i = 0; i < 2; i++)
#pragma unroll
        for (int j = 0; j < 4; j++) acc[i][j] = (floatx4){0.f, 0.f, 0.f, 0.f};

    const int srow = tid >> 3;
    const int skq = (tid & 7) * 8;

    for (int kc = 0; kc < 512; kc += BK) {
        const __bf16* Asrc = (kc >= 256) ? ag : hp;
        const int ks = kc & 255;
        *(bf16x8*)&As[srow * LSTR + skq] =
            *(const bf16x8*)(Asrc + (size_t)(row0 + srow) * HID + ks + skq);
#pragma unroll
        for (int r = 0; r < 4; r++) {
            int row = r * 64 + srow;
            *(bf16x8*)&Bs[row * LSTR + skq] =
                *(const bf16x8*)(W + (size_t)row * 512 + kc + skq);
        }
        __syncthreads();
#pragma unroll
        for (int s = 0; s < 2; s++) {
            bf16x8 af[2], bfr[4];
#pragma unroll
            for (int mt = 0; mt < 2; mt++)
                af[mt] = *(const bf16x8*)&As[(wm * 32 + mt * 16 + lr) * LSTR + s * 32 + lq * 8];
#pragma unroll
            for (int nt = 0; nt < 4; nt++)
                bfr[nt] = *(const bf16x8*)&Bs[(wn4 * 64 + nt * 16 + lr) * LSTR + s * 32 + lq * 8];
#pragma unroll
            for (int mt = 0; mt < 2; mt++)
#pragma unroll
                for (int nt = 0; nt < 4; nt++)
                    acc[mt][nt] = __builtin_amdgcn_mfma_f32_16x16x32_bf16(af[mt], bfr[nt], acc[mt][nt], 0, 0, 0);
        }
        __syncthreads();
    }

    __bf16 (*tile)[TSTR] = (__bf16(*)[TSTR])smem;
#pragma unroll
    for (int nt = 0; nt < 4; nt++) {
        const int col = wn4 * 64 + nt * 16 + lr;
        const float b = bias[col];
#pragma unroll
        for (int mt = 0; mt < 2; mt++) {
            const int lrow = wm * 32 + mt * 16 + lq * 4;
#pragma unroll
            for (int r = 0; r < 4; r++) {
                float res = (float)hp[(size_t)(row0 + lrow + r) * HID + col];
                float v = res + fmaxf(acc[mt][nt][r] + b, 0.f);
                tile[lrow + r][col] = (__bf16)v;
            }
        }
    }
    __syncthreads();

    if (wv < 4) {
        floatx4 facc[8];
#pragma unroll
        for (int j = 0; j < 8; j++) facc[j] = (floatx4){0.f, 0.f, 0.f, 0.f};
#pragma unroll
        for (int kt = 0; kt < 256; kt += 32) {
            bf16x8 a = *(const bf16x8*)&tile[wv * 16 + lr][kt + lq * 8];
            bf16x8 bf8[8];
#pragma unroll
            for (int nt = 0; nt < 8; nt++)
                bf8[nt] = *(const bf16x8*)(Wfc + (size_t)(nt * 16 + lr) * 256 + kt + lq * 8);
#pragma unroll
            for (int nt = 0; nt < 8; nt++)
                facc[nt] = __builtin_amdgcn_mfma_f32_16x16x32_bf16(a, bf8[nt], facc[nt], 0, 0, 0);
        }
        float s[4];
#pragma unroll
        for (int r = 0; r < 4; r++) {
            float t = 0.f;
#pragma unroll
            for (int nt = 0; nt < 8; nt++) t = fmaf(facc[nt][r], facc[nt][r], t);
            s[r] = t;
        }
#pragma unroll
        for (int mask = 1; mask <= 8; mask <<= 1) {
#pragma unroll
            for (int r = 0; r < 4; r++) s[r] += __shfl_xor(s[r], mask);
        }
        float inv[4];
#pragma unroll
        for (int r = 0; r < 4; r++) inv[r] = rsqrtf(s[r]);
#pragma unroll
        for (int r = 0; r < 4; r++) {
            int row = row0 + wv * 16 + lq * 4 + r;
            if (row >= N_NODES) continue;
#pragma unroll
            for (int nt = 0; nt < 8; nt++)
                outp[(size_t)row * OUT_FEAT + nt * 16 + lr] = facc[nt][r] * inv[r];
        }
    }
}

// ================= launch =================

extern "C" void kernel_launch(void* const* d_in, const int* in_sizes, int n_in,
                              void* d_out, int out_size, void* d_ws, size_t ws_size,
                              hipStream_t stream) {
    const float* x        = (const float*)d_in[0];
    const int*   edge_src = (const int*)d_in[1];
    const int*   edge_dst = (const int*)d_in[2];
    const float* edge_w   = (const float*)d_in[3];
    const float* W_emb    = (const float*)d_in[4];
    const float* W_gc1    = (const float*)d_in[5];
    const float* b_gc1    = (const float*)d_in[6];
    const float* W_gc2    = (const float*)d_in[7];
    const float* b_gc2    = (const float*)d_in[8];
    const float* W_fc     = (const float*)d_in[9];
    float* out = (float*)d_out;

    // ---- workspace layout ----
    char* p = (char*)d_ws;
    const size_t HROW = (size_t)MPAD * HID;
    __bf16* hb0   = (__bf16*)p;             p += HROW * 2;        // h0
    __bf16* hb1   = (__bf16*)p;             p += HROW * 2;        // h1
    __bf16* aggb  = (__bf16*)p;             p += HROW * 2;        // agg
    unsigned char* h8 = (unsigned char*)p;  p += HROW;            // int8 shadow (h0 then h1)
    float*  scl   = (float*)p;              p += (size_t)MPAD * 4;
    __bf16* w1b   = (__bf16*)p;             p += 131072 * 2;
    __bf16* w2b   = (__bf16*)p;             p += 131072 * 2;
    __bf16* wfcb  = (__bf16*)p;             p += 32768 * 2;
    int2*   edges = (int2*)p;               p += (size_t)N_NODES * CAP * 8;
    int*    counts = (int*)p;               p += (size_t)MPAD * 4;

    // N1: zero counts
    hipMemsetAsync(counts, 0, (size_t)MPAD * 4, stream);

    // N2: emb GEMM (+int8 shadow) + scatter + W convert
    front_kernel<<<EMB_BLK + SCAT_BLK + CONV_BLK, 512, 0, stream>>>(
        x, W_emb, hb0, h8, scl, edge_src, edge_dst, edge_w, counts, edges,
        W_gc1, W_gc2, W_fc, w1b, w2b, wfcb);

    // N3: agg1 = A @ h0 (int8 gather)
    aggregate_kernel<<<N_NODES / 8, 256, 0, stream>>>(h8, scl, counts, edges, aggb);

    // N4: h1 = h0 + relu([h0|agg1] @ W1^T + b1) (+int8 shadow)
    gconv1_kernel<<<MPAD / 64, 512, 0, stream>>>(hb0, aggb, w1b, b_gc1, hb1, h8, scl);

    // N5: agg2 = A @ h1 (int8 gather)
    aggregate_kernel<<<N_NODES / 8, 256, 0, stream>>>(h8, scl, counts, edges, aggb);

    // N6: h2 = h1 + relu([h1|agg2] @ W2^T + b2); out = normalize(h2 @ Wfc^T)
    gconv_fc_kernel<<<MPAD / 64, 512, 0, stream>>>(hb1, aggb, w2b, b_gc2, wfcb, out);
}